// Round 12
// baseline (141.744 us; speedup 1.0000x reference)
//
#include <hip/hip_runtime.h>

// ---------------------------------------------------------------------------
// HybridLossDynamic: total = mse + ssim_loss + 0.7*gme over (2,1,128,128,128)
// fp32 volumes. Outputs: [total, mse, ssim_loss, gme].
//
// r26 = r25 (137.6 us, best) + sobel-tail + zb-amplification fixes:
//   * fa: sobel 16 slices/block (2048 units), grid 4096 bid&1-in-wg split.
//     r17's version of this failed on +5MB halo FETCH; r24/r25's locality
//     alignment now absorbs the halo in L2 (fa FETCH measured at the 30MB
//     compulsory minimum). Halving the 34-step barrier'd sobel chain
//     attacks fa's low-occupancy tail (occ 39%, VALU 50% — latency-bound).
//     Aligned decode preserved: sobel z0c tracks wblur z at same wg.
//   * zb: 8 z-outputs/thread (zblur 1024 blocks + edge 1024, grid 2048).
//     Read amplification 14/4=3.5x -> 18/8=2.25x (-40MB L2 traffic),
//     18 independent loads/thread for deeper memory-level parallelism.
//   * fb: UNCHANGED this round (isolate the experiment).
//   * fminS/fmaxS grow to 2048 (vol-major); ssimS shrinks to 1024.
//
// SSIM chain: 4 fields {s,d,ss,dd}, s=p+t, d=p-t (r15, exact algebra).
// Interleaved [voxel][4 fields] (r18). Zero-LDS fb/zb (r21). Atomic-free
// plain-store accumulators, no memset (r23). XCD-chunk swizzles (r24).
//
// Measured lessons pinned (DO NOT REVISIT):
//   r7:  y+z fusion -> scattered 16B staging, 200MB HBM. REGRESSED
//   r9/r16: per-block threadfence+counter fold >100us. Final fold = own launch.
//   r10/r11: x+y WHOLE-TILE fusion, 63KB/2 blocks/CU. REGRESSED
//   r12: thin per-field slabs -> 5x barrier-latency exposure. REGRESSED
//   r15/r17/r23: SQ_LDS_BANK_CONFLICT = benign aliasing. Not the lever.
//   r19: fa is NOT barrier-bound.
//   r20: unequal per-role LDS in fused kernel collapses occupancy for all.
//   r22: NEVER grid.sync on MI355X (657us: XCD L2 writeback + spin).
//   r25: fa fetch = compulsory 30MB now; fa is latency/VALU-bound, NOT
//     HBM-bound. Stop chasing fa traffic.
//
// ws: A [0,32) MiB | B [32,64) | acc @80 MiB | gm @84 MiB (16 MiB).
// ---------------------------------------------------------------------------

#define VOL 4194304        // 2*128^3 (both batch images)
#define HV  2097152        // one batch image, 128^3

typedef _Float16 h2 __attribute__((ext_vector_type(2)));
typedef _Float16 h4 __attribute__((ext_vector_type(4)));
typedef _Float16 h8 __attribute__((ext_vector_type(8)));

// 11-tap Gaussian, sigma=1.5, normalized:
constexpr float GW[11] = {
    0.00102838f, 0.00759876f, 0.03600077f, 0.10936070f, 0.21300554f,
    0.26601173f,
    0.21300554f, 0.10936070f, 0.03600077f, 0.00759876f, 0.00102838f};

// Accumulator layout @80MiB (no init required — each slot stored once):
//   mseS: 2048 dbl @0 | ssimS: 1024 dbl @+16384 | absS: 1024 dbl @+24576
//   fminS: 2048 f32 @+32768 | fmaxS: 2048 f32 @+40960  (vol-major index)

// ---- role: W-blur, 2 voxels/thread, ONE barrier (r23) ----------------------
__device__ __forceinline__ void wblur_body(
    const float* __restrict__ p, const float* __restrict__ t,
    _Float16* __restrict__ A, double* __restrict__ mseS, const int unit,
    char* __restrict__ pool, float* __restrict__ redw) {
  float (* __restrict__ sr)[140] = (float (*)[140])pool;          // 8960 B
  float (* __restrict__ dr)[140] = (float (*)[140])(pool + 8960); // 8960 B
  const int tid = threadIdx.x;
  const int gbase = unit << 11;              // 16 rows * 128 voxels
  if (tid < 192) {                           // zero 12 pad cols per row
    const int r = tid / 12, j = tid % 12;
    const int c = (j < 6) ? j : (128 + j);   // {0..5, 134..139}
    sr[r][c] = 0.f; dr[r][c] = 0.f;
  }
  float msel = 0.f;
  const float2* __restrict__ p2 = (const float2*)(p + gbase);
  const float2* __restrict__ t2 = (const float2*)(t + gbase);
#pragma unroll
  for (int i = 0; i < 4; ++i) {              // 1024 pairs = 2048 voxels
    const int u = (i << 8) + tid;
    const int row = u >> 6, xp = u & 63;     // 64 pairs per row
    const float2 pv = p2[u];
    const float2 tv = t2[u];
    const float s0 = pv.x + tv.x, d0 = pv.x - tv.x;
    const float s1 = pv.y + tv.y, d1 = pv.y - tv.y;
    msel += d0 * d0;
    msel += d1 * d1;
    *(float2*)&sr[row][6 + (xp << 1)] = make_float2(s0, s1);
    *(float2*)&dr[row][6 + (xp << 1)] = make_float2(d0, d1);
  }
  __syncthreads();                           // THE barrier
  h8* __restrict__ A8 = (h8*)A;
#pragma unroll
  for (int i = 0; i < 4; ++i) {
    const int u = (i << 8) + tid;
    const int row = u >> 6, x0 = (u & 63) << 1;
    float as0 = 0.f, ad0 = 0.f, ass0 = 0.f, add0 = 0.f;
    float as1 = 0.f, ad1 = 0.f, ass1 = 0.f, add1 = 0.f;
#pragma unroll
    for (int k = 0; k < 11; ++k) {
      const float w = GW[k];
      const float a0 = sr[row][1 + x0 + k];
      const float b0 = dr[row][1 + x0 + k];
      const float wa0 = w * a0, wb0 = w * b0;
      as0 += wa0; ad0 += wb0; ass0 += wa0 * a0; add0 += wb0 * b0;
      const float a1 = sr[row][2 + x0 + k];
      const float b1 = dr[row][2 + x0 + k];
      const float wa1 = w * a1, wb1 = w * b1;
      as1 += wa1; ad1 += wb1; ass1 += wa1 * a1; add1 += wb1 * b1;
    }
    h8 o;
    o[0] = (_Float16)as0;  o[1] = (_Float16)ad0;
    o[2] = (_Float16)ass0; o[3] = (_Float16)add0;
    o[4] = (_Float16)as1;  o[5] = (_Float16)ad1;
    o[6] = (_Float16)ass1; o[7] = (_Float16)add1;
    A8[(gbase >> 1) + u] = o;                // 16B/lane, 1KB/wave
  }
  redw[tid] = msel;
  __syncthreads();
  for (int s = 128; s > 0; s >>= 1) {
    if (tid < s) redw[tid] += redw[tid + s];
    __syncthreads();
  }
  if (tid == 0) mseS[unit] = (double)redw[0];   // plain store, once
}

// ---- role: Sobel via separable s/d/u decomposition, 16 slices/block --------
__device__ __forceinline__ void sobel_body(
    const float* __restrict__ p, const float* __restrict__ t,
    _Float16* __restrict__ gmP, _Float16* __restrict__ gmT,
    float* __restrict__ fminS, float* __restrict__ fmaxS,
    const int bx, const int by, const int bz, const int sidx,
    char* __restrict__ pool, float* __restrict__ rmin) {
  float* __restrict__ sb   = (float*)pool;           // 1296*4 = 5184 B
  float* __restrict__ rmax = (float*)(pool + 5184);  // 1024 B
  const int tid = threadIdx.x;
  const int tx = tid & 15;
  const int ty = tid >> 4;
  const int x0 = bx << 4;
  const int y0 = by << 4;
  const int vol = bz >> 4;                   // bz in 0..31
  const int b   = (bz >> 3) & 1;
  const int z0  = (bz & 7) << 4;             // 16-slice chunks
  const float* __restrict__ img = vol ? t : p;
  _Float16* __restrict__ gm = vol ? gmT : gmP;
  const int vb = b << 21;

  // staging slots: pass1 = tid, pass2 = tid+256 (rows 0..17, stride 24)
  const int ly1 = tid / 24, lx1 = tid % 24;
  const bool v1 = (lx1 < 18);
  int gy1 = y0 - 1 + ly1; gy1 = gy1 < 0 ? 1 : (gy1 > 127 ? 126 : gy1);
  int gx1 = x0 - 1 + lx1; gx1 = gx1 < 0 ? 1 : (gx1 > 127 ? 126 : gx1);
  const int off1 = (gy1 << 7) + gx1;
  const int s2i = tid + 256;
  const int ly2 = s2i / 24, lx2 = s2i % 24;
  const bool v2 = (s2i < 432) && (lx2 < 18);
  int gy2 = y0 - 1 + ly2; gy2 = gy2 < 0 ? 1 : (gy2 > 127 ? 126 : gy2);
  int gx2 = x0 - 1 + lx2; gx2 = gx2 < 0 ? 1 : (gx2 > 127 ? 126 : gx2);
  const int off2 = (gy2 << 7) + gx2;
  const int rb = ty * 24 + tx;
  const int gbase = vb + (z0 << 14) + ((y0 + ty) << 7) + (x0 + tx);

  float Y0[7], Y1[7], Y2[7];
  float rv1 = 0.f, rv2 = 0.f;
  float lmin = 3.4e38f, lmax = 0.f;

#define LOADR(ZS) {                                                         \
    const int zc_ = (ZS) > 127 ? 126 : (ZS);                                \
    const int za_ = vb + (zc_ << 14);                                       \
    if (v1) rv1 = img[za_ + off1];                                          \
    if (v2) rv2 = img[za_ + off2]; }

#define WRITELDS(BOFF) {                                                    \
    if (v1) sb[(BOFF) + tid] = rv1;                                         \
    if (v2) sb[(BOFF) + s2i] = rv2; }

#define COMPY(P) {                                                          \
    const int o_ = (P) * 432 + rb;                                          \
    const float r00 = sb[o_],      r01 = sb[o_ + 1],  r02 = sb[o_ + 2];     \
    const float r10 = sb[o_ + 24], r11 = sb[o_ + 25], r12 = sb[o_ + 26];    \
    const float r20 = sb[o_ + 48], r21 = sb[o_ + 49], r22 = sb[o_ + 50];    \
    const float dx0 = r02 - r00, dx1 = r12 - r10, dx2 = r22 - r20;          \
    const float ux0 = r00 + r01 + r02, ux1 = r10 + r11 + r12,               \
                ux2 = r20 + r21 + r22;                                      \
    const float sx0 = ux0 + r01, sx1 = ux1 + r11, sx2 = ux2 + r21;          \
    Y##P[1] = dx0 + dx1 + dx2;           /* uydx */                         \
    Y##P[0] = Y##P[1] + dx1;             /* sydx */                         \
    Y##P[2] = sx2 - sx0;                 /* dysx */                         \
    Y##P[4] = sx0 + sx1 + sx2;           /* uysx */                         \
    Y##P[3] = Y##P[4] + sx1;             /* sysx */                         \
    Y##P[5] = ux2 - ux0;                 /* dyux */                         \
    Y##P[6] = (ux0 + ux2) + 2.f * ux1; } /* syux */

#define EMIT(I, P0, P1, P2) {                                               \
    const float E_ = Y##P0[0] + Y##P1[0] + Y##P2[0];                        \
    const float g1 = E_ + Y##P1[0];                                         \
    const float tA = Y##P0[1] + Y##P1[1] + Y##P2[1];                        \
    const float A_ = tA + Y##P1[1];                                         \
    const float D_ = Y##P0[2] + Y##P1[2] + Y##P2[2];                        \
    const float g2 = D_ + Y##P1[2];                                         \
    const float g3 = Y##P2[3] - Y##P0[3];                                   \
    const float C_ = Y##P2[4] - Y##P0[4];                                   \
    const float B_ = (Y##P0[5] + Y##P2[5]) + 2.f * Y##P1[5];                \
    const float F_ = Y##P2[6] - Y##P0[6];                                   \
    const float g4 = A_ - B_, g5 = A_ + B_;                                 \
    const float g6 = C_ - D_, g7 = C_ + D_;                                 \
    const float g8 = E_ - F_, g9 = E_ + F_;                                 \
    float ss_ = 9e-6f, t_;                                                  \
    t_ = g1 + 1e-6f; ss_ = fmaf(t_, t_, ss_);                               \
    t_ = g2 + 1e-6f; ss_ = fmaf(t_, t_, ss_);                               \
    t_ = g3 + 1e-6f; ss_ = fmaf(t_, t_, ss_);                               \
    t_ = g4 + 1e-6f; ss_ = fmaf(t_, t_, ss_);                               \
    t_ = g5 + 1e-6f; ss_ = fmaf(t_, t_, ss_);                               \
    t_ = g6 + 1e-6f; ss_ = fmaf(t_, t_, ss_);                               \
    t_ = g7 + 1e-6f; ss_ = fmaf(t_, t_, ss_);                               \
    t_ = g8 + 1e-6f; ss_ = fmaf(t_, t_, ss_);                               \
    t_ = g9 + 1e-6f; ss_ = fmaf(t_, t_, ss_);                               \
    const _Float16 gh = (_Float16)sqrtf(ss_);                               \
    gm[gbase + ((I) << 14)] = gh;                                           \
    const float gq = (float)gh;                                             \
    lmin = fminf(lmin, gq); lmax = fmaxf(lmax, gq); }

#define BODY(I, P0, P1, P2) {                                               \
    WRITELDS((P2) * 432);                                                   \
    LOADR(z0 + (I) + 2);                                                    \
    __syncthreads();                                                        \
    COMPY(P2);                                                              \
    EMIT(I, P0, P1, P2); }

  {
    const int zp = (z0 == 0) ? 1 : (z0 - 1);
    LOADR(zp);  WRITELDS(0);
    LOADR(z0);  WRITELDS(432);
    __syncthreads();
    COMPY(0);
    COMPY(1);
    LOADR(z0 + 1);                           // prime the pipeline
  }
  for (int ii = 0; ii < 15; ii += 3) {
    BODY(ii,     0, 1, 2);
    BODY(ii + 1, 1, 2, 0);
    BODY(ii + 2, 2, 0, 1);
  }
  BODY(15, 0, 1, 2);

#undef BODY
#undef EMIT
#undef COMPY
#undef WRITELDS
#undef LOADR

  rmin[tid] = lmin; rmax[tid] = lmax;
  __syncthreads();
  for (int st = 128; st > 0; st >>= 1) {
    if (tid < st) {
      rmin[tid] = fminf(rmin[tid], rmin[tid + st]);
      rmax[tid] = fmaxf(rmax[tid], rmax[tid + st]);
    }
    __syncthreads();
  }
  if (tid == 0) {                            // plain stores, once per call
    fminS[sidx] = rmin[0];
    fmaxS[sidx] = rmax[0];
  }
}

// ---- L1: wblur || sobel (wg&1), XCD-chunk swizzle + aligned decode ---------
__global__ __launch_bounds__(256) void k_fused_a(
    const float* __restrict__ p, const float* __restrict__ t,
    _Float16* __restrict__ A, double* __restrict__ mseS,
    _Float16* __restrict__ gmP, _Float16* __restrict__ gmT,
    float* __restrict__ fminS, float* __restrict__ fmaxS) {
  __shared__ __align__(16) char pool[17920];  // wblur sr+dr | sobel sb+rmax
  __shared__ float redshared[256];
  const int bid = blockIdx.x;                 // 0..4095
  const int wg = ((bid & 7) << 9) + (bid >> 3);    // XCD-chunk (bijective)
  if ((wg & 1) == 0) {
    wblur_body(p, t, A, mseS, wg >> 1, pool, redshared);     // 0..2047
  } else {
    const int s = wg >> 1;                    // 0..2047
    // aligned decode: wblur z at s = (s&1023)>>3 -> z0c = (s&1023)>>7.
    const int b   = s >> 10;
    const int rem = s & 1023;
    const int z0c = rem >> 7;
    const int vol = (rem >> 6) & 1;
    const int by  = (rem >> 3) & 7;
    const int bx  = rem & 7;
    const int bz  = (vol << 4) + (b << 3) + z0c;
    const int sidx = (vol << 10) + (b << 9) + (z0c << 6) + (by << 3) + bx;
    sobel_body(p, t, gmP, gmT, fminS, fmaxS, bx, by, bz, sidx,
               pool, redshared);
  }
}

// ---- L2: y-blur, zero LDS, XCD-chunk + yseg-fastest (r25 unchanged) --------
__global__ __launch_bounds__(256) void k_fused_b(
    const _Float16* __restrict__ A, _Float16* __restrict__ B) {
  const int bid = blockIdx.x;                 // 0..2047
  const int wg = ((bid & 7) << 8) + (bid >> 3);    // XCD-chunk (bijective)
  const int yseg = wg & 7;
  const int z = (wg >> 3) & 127;
  const int batch = wg >> 10;
  const int tid = threadIdx.x;
  const int xc = tid & 63;
  const int yg = tid >> 6;                    // 0..3
  const h8* __restrict__ Ah = (const h8*)A;
  h8* __restrict__ Bh = (h8*)B;
  const int slice8 = (batch << 20) + (z << 13);   // h8 idx of (b,z,0,0)
  const int ybase = (yseg << 4) + (yg << 2);      // first output row
  h8 acc0{}, acc1{}, acc2{}, acc3{};
#pragma unroll
  for (int k = 0; k < 14; ++k) {
    const int y = ybase - 5 + k;
    h8 rv{};
    if ((unsigned)y < 128u) rv = Ah[slice8 + (y << 6) + xc];
    if (k <= 10)           acc0 += (_Float16)GW[k]      * rv;
    if (k >= 1 && k <= 11) acc1 += (_Float16)GW[k - 1]  * rv;
    if (k >= 2 && k <= 12) acc2 += (_Float16)GW[k - 2]  * rv;
    if (k >= 3)            acc3 += (_Float16)GW[k - 3]  * rv;
  }
  const int wbase = slice8 + (ybase << 6) + xc;
  Bh[wbase]            = acc0;
  Bh[wbase + (1 << 6)] = acc1;
  Bh[wbase + (2 << 6)] = acc2;
  Bh[wbase + (3 << 6)] = acc3;
}

// ---- role: mean |norm_p - norm_t|; min/max re-reduced from arrays ----------
__device__ __forceinline__ void edge_body(
    const _Float16* __restrict__ gmP, const _Float16* __restrict__ gmT,
    const float* __restrict__ fminS, const float* __restrict__ fmaxS,
    double* __restrict__ absS, const int bidx,
    float* __restrict__ scr, float* __restrict__ rede) {
  float* __restrict__ rm0 = scr;             // 4 x 256 floats
  float* __restrict__ rM0 = scr + 256;
  float* __restrict__ rm1 = scr + 512;
  float* __restrict__ rM1 = scr + 768;
  const int tid = threadIdx.x;
  float mnp = 3.4e38f, mxp = 0.f, mnt = 3.4e38f, mxt = 0.f;
  for (int j = tid; j < 1024; j += 256) {    // vol0 = 0..1023 (vol-major idx)
    mnp = fminf(mnp, fminS[j]);
    mxp = fmaxf(mxp, fmaxS[j]);
    mnt = fminf(mnt, fminS[1024 + j]);       // vol1 = 1024..2047
    mxt = fmaxf(mxt, fmaxS[1024 + j]);
  }
  rm0[tid] = mnp; rM0[tid] = mxp; rm1[tid] = mnt; rM1[tid] = mxt;
  __syncthreads();
  for (int s = 128; s > 0; s >>= 1) {
    if (tid < s) {
      rm0[tid] = fminf(rm0[tid], rm0[tid + s]);
      rM0[tid] = fmaxf(rM0[tid], rM0[tid + s]);
      rm1[tid] = fminf(rm1[tid], rm1[tid + s]);
      rM1[tid] = fmaxf(rM1[tid], rM1[tid + s]);
    }
    __syncthreads();
  }
  mnp = rm0[0]; mxp = rM0[0]; mnt = rm1[0]; mxt = rM1[0];
  const float scp = 1.f / (mxp - mnp + 1e-6f);
  const float sct = 1.f / (mxt - mnt + 1e-6f);
  const h8* __restrict__ gp = (const h8*)gmP;
  const h8* __restrict__ gt = (const h8*)gmT;
  float lsum = 0.f;
  const int base = bidx << 9;                      // 512 h8 per block
#pragma unroll
  for (int i = 0; i < 2; ++i) {
    const int idx = base + (i << 8) + tid;
    const h8 a = gp[idx];
    const h8 b = gt[idx];
#pragma unroll
    for (int j = 0; j < 8; ++j)
      lsum += fabsf(((float)a[j] - mnp) * scp - ((float)b[j] - mnt) * sct);
  }
  rede[tid] = lsum;
  __syncthreads();
  for (int s = 128; s > 0; s >>= 1) {
    if (tid < s) rede[tid] += rede[tid + s];
    __syncthreads();
  }
  if (tid == 0) absS[bidx] = (double)rede[0];   // plain store, once
}

// ---- L3: z-blur+ssim (8 z/thread, zero-LDS) || edge (wg&1) -----------------
// SSIM from s/d fields: S2=mus^2, D2=mud^2:
//   num = ((S2-D2)/2 + C1) * ((G(ss)-G(dd)-S2+D2)/2 + C2)
//   den = ((S2+D2)/2 + C1) * ((G(ss)+G(dd)-S2-D2)/2 + C2)
__global__ __launch_bounds__(256) void k_zblur_ssim(
    const _Float16* __restrict__ B, double* __restrict__ ssimS,
    const _Float16* __restrict__ gmP, const _Float16* __restrict__ gmT,
    const float* __restrict__ fminS, const float* __restrict__ fmaxS,
    double* __restrict__ absS) {
  __shared__ float scr[1024];
  __shared__ float red[256];
  const int tid = threadIdx.x;
  const int bid = blockIdx.x;                 // 0..2047
  const int wg = ((bid & 7) << 8) + (bid >> 3);    // XCD-chunk (bijective)
  if (wg & 1) {
    edge_body(gmP, gmT, fminS, fmaxS, absS, wg >> 1, scr, red);   // 0..1023
    return;
  }
  const int u = wg >> 1;                      // 0..1023
  const int zseg = u & 3;                     // zseg fastest: halo adjacency
  const int y = (u >> 2) & 127;
  const int batch = u >> 9;
  const int xc = tid & 63;
  const int zg = tid >> 6;                    // 0..3
  const h8* __restrict__ Bh = (const h8*)B;
  const int col8 = (batch << 20) + (y << 6);  // h8 idx of (b,0,y,0)
  const int zbase = (zseg << 5) + (zg << 3);  // first of 8 output z's
  h8 m[8] = {};
#pragma unroll
  for (int k = 0; k < 18; ++k) {
    const int zz = zbase - 5 + k;
    h8 rv{};
    if ((unsigned)zz < 128u) rv = Bh[col8 + (zz << 13) + xc];
#pragma unroll
    for (int r = 0; r < 8; ++r)
      if (k >= r && k <= r + 10) m[r] += (_Float16)GW[k - r] * rv;
  }
  float lsum = 0.f;
#pragma unroll
  for (int r = 0; r < 8; ++r) {
#pragma unroll
    for (int j = 0; j < 2; ++j) {             // 2 voxels per h8
      const float mus = (float)m[r][4 * j + 0];
      const float mud = (float)m[r][4 * j + 1];
      const float ess = (float)m[r][4 * j + 2];
      const float edd = (float)m[r][4 * j + 3];
      const float S2 = mus * mus, D2 = mud * mud;
      const float num = ((S2 - D2) * 0.5f + 1e-4f) *
                        ((ess - edd - S2 + D2) * 0.5f + 9e-4f);
      const float den = ((S2 + D2) * 0.5f + 1e-4f) *
                        ((ess + edd - S2 - D2) * 0.5f + 9e-4f);
      lsum += num / den;
    }
  }
  red[tid] = lsum;
  __syncthreads();
  for (int st = 128; st > 0; st >>= 1) {
    if (tid < st) red[tid] += red[tid + st];
    __syncthreads();
  }
  if (tid == 0) ssimS[u] = (double)red[0];    // plain store, once
}

// ---- final: 256-lane parallel fold of the plain-store bins -----------------
__global__ __launch_bounds__(256) void k_final(
    const double* __restrict__ mseS, const double* __restrict__ ssimS,
    const double* __restrict__ absS, float* __restrict__ out) {
  __shared__ double dred[256];
  const int tid = threadIdx.x;
  double msl = 0.0, ssl = 0.0, abl = 0.0;
  for (int j = tid; j < 2048; j += 256) msl += mseS[j];
  for (int j = tid; j < 1024; j += 256) { ssl += ssimS[j]; abl += absS[j]; }
  dred[tid] = msl; __syncthreads();
  for (int s = 128; s > 0; s >>= 1) {
    if (tid < s) dred[tid] += dred[tid + s];
    __syncthreads();
  }
  const double ms = dred[0]; __syncthreads();
  dred[tid] = ssl; __syncthreads();
  for (int s = 128; s > 0; s >>= 1) {
    if (tid < s) dred[tid] += dred[tid + s];
    __syncthreads();
  }
  const double ss = dred[0]; __syncthreads();
  dred[tid] = abl; __syncthreads();
  for (int s = 128; s > 0; s >>= 1) {
    if (tid < s) dred[tid] += dred[tid + s];
    __syncthreads();
  }
  if (tid == 0) {
    const double ab = dred[0];
    const double N = 4194304.0;
    const double mse   = ms / N;
    const double ssiml = 1.0 - ss / N;
    const double gme   = 1e-6 + ab / N;
    const double total = mse + ssiml + 0.7 * gme;
    out[0] = (float)total;
    out[1] = (float)mse;
    out[2] = (float)ssiml;
    out[3] = (float)gme;
  }
}

extern "C" void kernel_launch(void* const* d_in, const int* in_sizes, int n_in,
                              void* d_out, int out_size, void* d_ws, size_t ws_size,
                              hipStream_t stream) {
  const float* p = (const float*)d_in[0];
  const float* t = (const float*)d_in[1];
  _Float16* A = (_Float16*)d_ws;                    // 32 MiB
  _Float16* B = A + (size_t)4 * VOL;                // 32 MiB @ 32 MiB
  char* accb = (char*)d_ws + (size_t)20 * VOL;      // @80 MiB
  double* mseS  = (double*)accb;                    // 2048 dbl
  double* ssimS = (double*)(accb + 16384);          // 1024 dbl
  double* absS  = (double*)(accb + 24576);          // 1024 dbl
  float*  fminS = (float*)(accb + 32768);           // 2048 f32
  float*  fmaxS = (float*)(accb + 40960);           // 2048 f32
  _Float16* gmP = (_Float16*)((char*)d_ws + 88080384);  // @84 MiB, 16 MiB
  _Float16* gmT = gmP + VOL;
  float* out = (float*)d_out;

  k_fused_a<<<4096, 256, 0, stream>>>(p, t, A, mseS, gmP, gmT, fminS, fmaxS);
  k_fused_b<<<2048, 256, 0, stream>>>(A, B);
  k_zblur_ssim<<<2048, 256, 0, stream>>>(B, ssimS, gmP, gmT, fminS, fmaxS,
                                         absS);
  k_final<<<1, 256, 0, stream>>>(mseS, ssimS, absS, out);
}

// Round 13
// 135.309 us; speedup vs baseline: 1.0476x; 1.0476x over previous
//
#include <hip/hip_runtime.h>

// ---------------------------------------------------------------------------
// HybridLossDynamic: total = mse + ssim_loss + 0.7*gme over (2,1,128,128,128)
// fp32 volumes. Outputs: [total, mse, ssim_loss, gme].
//
// r27 = split-revert of r26 (141.7):
//   * KEEP fa's 16-slice sobel (fa 47.6 -> 46.0 us, FETCH 22.6MB ~ compulsory).
//   * REVERT zb to r25's 4-z/thread (r26's 8-z/thread cost ~5.5us: 32 VGPR
//     of h8 accumulators + 18-deep 8-way predicated tap fan-out + halved
//     block count. 4 z/thread is the sweet spot — PINNED).
//   * fb unchanged. fmin/fmax stay 2048-entry vol-major (16-slice sobel).
//
// SSIM chain: 4 fields {s,d,ss,dd}, s=p+t, d=p-t (r15, exact algebra).
// Interleaved [voxel][4 fields] (r18). Zero-LDS fb/zb (r21). Atomic-free
// plain-store accumulators, no memset (r23). XCD-chunk swizzles + aligned
// sobel decode (r24/r25).
//
// Measured lessons pinned (DO NOT REVISIT):
//   r7:  y+z fusion -> scattered 16B staging, 200MB HBM. REGRESSED
//   r9/r16: per-block threadfence+counter fold >100us. Final fold = own launch.
//   r10/r11: x+y WHOLE-TILE fusion, 63KB/2 blocks/CU. REGRESSED
//   r12: thin per-field slabs -> 5x barrier-latency exposure. REGRESSED
//   r15/r17/r23: SQ_LDS_BANK_CONFLICT = benign aliasing. Not the lever.
//   r19: fa is NOT barrier-bound.
//   r20: unequal per-role LDS in fused kernel collapses occupancy for all.
//   r22: NEVER grid.sync on MI355X (657us: XCD L2 writeback + spin).
//   r25: fa fetch = compulsory now; fa is latency/VALU-bound, not HBM-bound.
//   r26: zb 8-z/thread REGRESSED (~5.5us). 4 z/thread is the sweet spot.
//
// ws: A [0,32) MiB | B [32,64) | acc @80 MiB | gm @84 MiB (16 MiB).
// ---------------------------------------------------------------------------

#define VOL 4194304        // 2*128^3 (both batch images)
#define HV  2097152        // one batch image, 128^3

typedef _Float16 h2 __attribute__((ext_vector_type(2)));
typedef _Float16 h4 __attribute__((ext_vector_type(4)));
typedef _Float16 h8 __attribute__((ext_vector_type(8)));

// 11-tap Gaussian, sigma=1.5, normalized:
constexpr float GW[11] = {
    0.00102838f, 0.00759876f, 0.03600077f, 0.10936070f, 0.21300554f,
    0.26601173f,
    0.21300554f, 0.10936070f, 0.03600077f, 0.00759876f, 0.00102838f};

// Accumulator layout @80MiB (no init required — each slot stored once):
//   mseS: 2048 dbl @0 | ssimS: 2048 dbl @+16384 | absS: 1024 dbl @+32768
//   fminS: 2048 f32 @+40960 | fmaxS: 2048 f32 @+49152  (vol-major index)

// ---- role: W-blur, 2 voxels/thread, ONE barrier (r23) ----------------------
__device__ __forceinline__ void wblur_body(
    const float* __restrict__ p, const float* __restrict__ t,
    _Float16* __restrict__ A, double* __restrict__ mseS, const int unit,
    char* __restrict__ pool, float* __restrict__ redw) {
  float (* __restrict__ sr)[140] = (float (*)[140])pool;          // 8960 B
  float (* __restrict__ dr)[140] = (float (*)[140])(pool + 8960); // 8960 B
  const int tid = threadIdx.x;
  const int gbase = unit << 11;              // 16 rows * 128 voxels
  if (tid < 192) {                           // zero 12 pad cols per row
    const int r = tid / 12, j = tid % 12;
    const int c = (j < 6) ? j : (128 + j);   // {0..5, 134..139}
    sr[r][c] = 0.f; dr[r][c] = 0.f;
  }
  float msel = 0.f;
  const float2* __restrict__ p2 = (const float2*)(p + gbase);
  const float2* __restrict__ t2 = (const float2*)(t + gbase);
#pragma unroll
  for (int i = 0; i < 4; ++i) {              // 1024 pairs = 2048 voxels
    const int u = (i << 8) + tid;
    const int row = u >> 6, xp = u & 63;     // 64 pairs per row
    const float2 pv = p2[u];
    const float2 tv = t2[u];
    const float s0 = pv.x + tv.x, d0 = pv.x - tv.x;
    const float s1 = pv.y + tv.y, d1 = pv.y - tv.y;
    msel += d0 * d0;
    msel += d1 * d1;
    *(float2*)&sr[row][6 + (xp << 1)] = make_float2(s0, s1);
    *(float2*)&dr[row][6 + (xp << 1)] = make_float2(d0, d1);
  }
  __syncthreads();                           // THE barrier
  h8* __restrict__ A8 = (h8*)A;
#pragma unroll
  for (int i = 0; i < 4; ++i) {
    const int u = (i << 8) + tid;
    const int row = u >> 6, x0 = (u & 63) << 1;
    float as0 = 0.f, ad0 = 0.f, ass0 = 0.f, add0 = 0.f;
    float as1 = 0.f, ad1 = 0.f, ass1 = 0.f, add1 = 0.f;
#pragma unroll
    for (int k = 0; k < 11; ++k) {
      const float w = GW[k];
      const float a0 = sr[row][1 + x0 + k];
      const float b0 = dr[row][1 + x0 + k];
      const float wa0 = w * a0, wb0 = w * b0;
      as0 += wa0; ad0 += wb0; ass0 += wa0 * a0; add0 += wb0 * b0;
      const float a1 = sr[row][2 + x0 + k];
      const float b1 = dr[row][2 + x0 + k];
      const float wa1 = w * a1, wb1 = w * b1;
      as1 += wa1; ad1 += wb1; ass1 += wa1 * a1; add1 += wb1 * b1;
    }
    h8 o;
    o[0] = (_Float16)as0;  o[1] = (_Float16)ad0;
    o[2] = (_Float16)ass0; o[3] = (_Float16)add0;
    o[4] = (_Float16)as1;  o[5] = (_Float16)ad1;
    o[6] = (_Float16)ass1; o[7] = (_Float16)add1;
    A8[(gbase >> 1) + u] = o;                // 16B/lane, 1KB/wave
  }
  redw[tid] = msel;
  __syncthreads();
  for (int s = 128; s > 0; s >>= 1) {
    if (tid < s) redw[tid] += redw[tid + s];
    __syncthreads();
  }
  if (tid == 0) mseS[unit] = (double)redw[0];   // plain store, once
}

// ---- role: Sobel via separable s/d/u decomposition, 16 slices/block --------
__device__ __forceinline__ void sobel_body(
    const float* __restrict__ p, const float* __restrict__ t,
    _Float16* __restrict__ gmP, _Float16* __restrict__ gmT,
    float* __restrict__ fminS, float* __restrict__ fmaxS,
    const int bx, const int by, const int bz, const int sidx,
    char* __restrict__ pool, float* __restrict__ rmin) {
  float* __restrict__ sb   = (float*)pool;           // 1296*4 = 5184 B
  float* __restrict__ rmax = (float*)(pool + 5184);  // 1024 B
  const int tid = threadIdx.x;
  const int tx = tid & 15;
  const int ty = tid >> 4;
  const int x0 = bx << 4;
  const int y0 = by << 4;
  const int vol = bz >> 4;                   // bz in 0..31
  const int b   = (bz >> 3) & 1;
  const int z0  = (bz & 7) << 4;             // 16-slice chunks
  const float* __restrict__ img = vol ? t : p;
  _Float16* __restrict__ gm = vol ? gmT : gmP;
  const int vb = b << 21;

  // staging slots: pass1 = tid, pass2 = tid+256 (rows 0..17, stride 24)
  const int ly1 = tid / 24, lx1 = tid % 24;
  const bool v1 = (lx1 < 18);
  int gy1 = y0 - 1 + ly1; gy1 = gy1 < 0 ? 1 : (gy1 > 127 ? 126 : gy1);
  int gx1 = x0 - 1 + lx1; gx1 = gx1 < 0 ? 1 : (gx1 > 127 ? 126 : gx1);
  const int off1 = (gy1 << 7) + gx1;
  const int s2i = tid + 256;
  const int ly2 = s2i / 24, lx2 = s2i % 24;
  const bool v2 = (s2i < 432) && (lx2 < 18);
  int gy2 = y0 - 1 + ly2; gy2 = gy2 < 0 ? 1 : (gy2 > 127 ? 126 : gy2);
  int gx2 = x0 - 1 + lx2; gx2 = gx2 < 0 ? 1 : (gx2 > 127 ? 126 : gx2);
  const int off2 = (gy2 << 7) + gx2;
  const int rb = ty * 24 + tx;
  const int gbase = vb + (z0 << 14) + ((y0 + ty) << 7) + (x0 + tx);

  float Y0[7], Y1[7], Y2[7];
  float rv1 = 0.f, rv2 = 0.f;
  float lmin = 3.4e38f, lmax = 0.f;

#define LOADR(ZS) {                                                         \
    const int zc_ = (ZS) > 127 ? 126 : (ZS);                                \
    const int za_ = vb + (zc_ << 14);                                       \
    if (v1) rv1 = img[za_ + off1];                                          \
    if (v2) rv2 = img[za_ + off2]; }

#define WRITELDS(BOFF) {                                                    \
    if (v1) sb[(BOFF) + tid] = rv1;                                         \
    if (v2) sb[(BOFF) + s2i] = rv2; }

#define COMPY(P) {                                                          \
    const int o_ = (P) * 432 + rb;                                          \
    const float r00 = sb[o_],      r01 = sb[o_ + 1],  r02 = sb[o_ + 2];     \
    const float r10 = sb[o_ + 24], r11 = sb[o_ + 25], r12 = sb[o_ + 26];    \
    const float r20 = sb[o_ + 48], r21 = sb[o_ + 49], r22 = sb[o_ + 50];    \
    const float dx0 = r02 - r00, dx1 = r12 - r10, dx2 = r22 - r20;          \
    const float ux0 = r00 + r01 + r02, ux1 = r10 + r11 + r12,               \
                ux2 = r20 + r21 + r22;                                      \
    const float sx0 = ux0 + r01, sx1 = ux1 + r11, sx2 = ux2 + r21;          \
    Y##P[1] = dx0 + dx1 + dx2;           /* uydx */                         \
    Y##P[0] = Y##P[1] + dx1;             /* sydx */                         \
    Y##P[2] = sx2 - sx0;                 /* dysx */                         \
    Y##P[4] = sx0 + sx1 + sx2;           /* uysx */                         \
    Y##P[3] = Y##P[4] + sx1;             /* sysx */                         \
    Y##P[5] = ux2 - ux0;                 /* dyux */                         \
    Y##P[6] = (ux0 + ux2) + 2.f * ux1; } /* syux */

#define EMIT(I, P0, P1, P2) {                                               \
    const float E_ = Y##P0[0] + Y##P1[0] + Y##P2[0];                        \
    const float g1 = E_ + Y##P1[0];                                         \
    const float tA = Y##P0[1] + Y##P1[1] + Y##P2[1];                        \
    const float A_ = tA + Y##P1[1];                                         \
    const float D_ = Y##P0[2] + Y##P1[2] + Y##P2[2];                        \
    const float g2 = D_ + Y##P1[2];                                         \
    const float g3 = Y##P2[3] - Y##P0[3];                                   \
    const float C_ = Y##P2[4] - Y##P0[4];                                   \
    const float B_ = (Y##P0[5] + Y##P2[5]) + 2.f * Y##P1[5];                \
    const float F_ = Y##P2[6] - Y##P0[6];                                   \
    const float g4 = A_ - B_, g5 = A_ + B_;                                 \
    const float g6 = C_ - D_, g7 = C_ + D_;                                 \
    const float g8 = E_ - F_, g9 = E_ + F_;                                 \
    float ss_ = 9e-6f, t_;                                                  \
    t_ = g1 + 1e-6f; ss_ = fmaf(t_, t_, ss_);                               \
    t_ = g2 + 1e-6f; ss_ = fmaf(t_, t_, ss_);                               \
    t_ = g3 + 1e-6f; ss_ = fmaf(t_, t_, ss_);                               \
    t_ = g4 + 1e-6f; ss_ = fmaf(t_, t_, ss_);                               \
    t_ = g5 + 1e-6f; ss_ = fmaf(t_, t_, ss_);                               \
    t_ = g6 + 1e-6f; ss_ = fmaf(t_, t_, ss_);                               \
    t_ = g7 + 1e-6f; ss_ = fmaf(t_, t_, ss_);                               \
    t_ = g8 + 1e-6f; ss_ = fmaf(t_, t_, ss_);                               \
    t_ = g9 + 1e-6f; ss_ = fmaf(t_, t_, ss_);                               \
    const _Float16 gh = (_Float16)sqrtf(ss_);                               \
    gm[gbase + ((I) << 14)] = gh;                                           \
    const float gq = (float)gh;                                             \
    lmin = fminf(lmin, gq); lmax = fmaxf(lmax, gq); }

#define BODY(I, P0, P1, P2) {                                               \
    WRITELDS((P2) * 432);                                                   \
    LOADR(z0 + (I) + 2);                                                    \
    __syncthreads();                                                        \
    COMPY(P2);                                                              \
    EMIT(I, P0, P1, P2); }

  {
    const int zp = (z0 == 0) ? 1 : (z0 - 1);
    LOADR(zp);  WRITELDS(0);
    LOADR(z0);  WRITELDS(432);
    __syncthreads();
    COMPY(0);
    COMPY(1);
    LOADR(z0 + 1);                           // prime the pipeline
  }
  for (int ii = 0; ii < 15; ii += 3) {
    BODY(ii,     0, 1, 2);
    BODY(ii + 1, 1, 2, 0);
    BODY(ii + 2, 2, 0, 1);
  }
  BODY(15, 0, 1, 2);

#undef BODY
#undef EMIT
#undef COMPY
#undef WRITELDS
#undef LOADR

  rmin[tid] = lmin; rmax[tid] = lmax;
  __syncthreads();
  for (int st = 128; st > 0; st >>= 1) {
    if (tid < st) {
      rmin[tid] = fminf(rmin[tid], rmin[tid + st]);
      rmax[tid] = fmaxf(rmax[tid], rmax[tid + st]);
    }
    __syncthreads();
  }
  if (tid == 0) {                            // plain stores, once per call
    fminS[sidx] = rmin[0];
    fmaxS[sidx] = rmax[0];
  }
}

// ---- L1: wblur || sobel (wg&1), XCD-chunk swizzle + aligned decode ---------
__global__ __launch_bounds__(256) void k_fused_a(
    const float* __restrict__ p, const float* __restrict__ t,
    _Float16* __restrict__ A, double* __restrict__ mseS,
    _Float16* __restrict__ gmP, _Float16* __restrict__ gmT,
    float* __restrict__ fminS, float* __restrict__ fmaxS) {
  __shared__ __align__(16) char pool[17920];  // wblur sr+dr | sobel sb+rmax
  __shared__ float redshared[256];
  const int bid = blockIdx.x;                 // 0..4095
  const int wg = ((bid & 7) << 9) + (bid >> 3);    // XCD-chunk (bijective)
  if ((wg & 1) == 0) {
    wblur_body(p, t, A, mseS, wg >> 1, pool, redshared);     // 0..2047
  } else {
    const int s = wg >> 1;                    // 0..2047
    // aligned decode: wblur z at s = (s&1023)>>3 -> z0c = (s&1023)>>7.
    const int b   = s >> 10;
    const int rem = s & 1023;
    const int z0c = rem >> 7;
    const int vol = (rem >> 6) & 1;
    const int by  = (rem >> 3) & 7;
    const int bx  = rem & 7;
    const int bz  = (vol << 4) + (b << 3) + z0c;
    const int sidx = (vol << 10) + (b << 9) + (z0c << 6) + (by << 3) + bx;
    sobel_body(p, t, gmP, gmT, fminS, fmaxS, bx, by, bz, sidx,
               pool, redshared);
  }
}

// ---- L2: y-blur, zero LDS, XCD-chunk + yseg-fastest (r25 unchanged) --------
__global__ __launch_bounds__(256) void k_fused_b(
    const _Float16* __restrict__ A, _Float16* __restrict__ B) {
  const int bid = blockIdx.x;                 // 0..2047
  const int wg = ((bid & 7) << 8) + (bid >> 3);    // XCD-chunk (bijective)
  const int yseg = wg & 7;
  const int z = (wg >> 3) & 127;
  const int batch = wg >> 10;
  const int tid = threadIdx.x;
  const int xc = tid & 63;
  const int yg = tid >> 6;                    // 0..3
  const h8* __restrict__ Ah = (const h8*)A;
  h8* __restrict__ Bh = (h8*)B;
  const int slice8 = (batch << 20) + (z << 13);   // h8 idx of (b,z,0,0)
  const int ybase = (yseg << 4) + (yg << 2);      // first output row
  h8 acc0{}, acc1{}, acc2{}, acc3{};
#pragma unroll
  for (int k = 0; k < 14; ++k) {
    const int y = ybase - 5 + k;
    h8 rv{};
    if ((unsigned)y < 128u) rv = Ah[slice8 + (y << 6) + xc];
    if (k <= 10)           acc0 += (_Float16)GW[k]      * rv;
    if (k >= 1 && k <= 11) acc1 += (_Float16)GW[k - 1]  * rv;
    if (k >= 2 && k <= 12) acc2 += (_Float16)GW[k - 2]  * rv;
    if (k >= 3)            acc3 += (_Float16)GW[k - 3]  * rv;
  }
  const int wbase = slice8 + (ybase << 6) + xc;
  Bh[wbase]            = acc0;
  Bh[wbase + (1 << 6)] = acc1;
  Bh[wbase + (2 << 6)] = acc2;
  Bh[wbase + (3 << 6)] = acc3;
}

// ---- role: mean |norm_p - norm_t|; min/max re-reduced from arrays ----------
__device__ __forceinline__ void edge_body(
    const _Float16* __restrict__ gmP, const _Float16* __restrict__ gmT,
    const float* __restrict__ fminS, const float* __restrict__ fmaxS,
    double* __restrict__ absS, const int bidx,
    float* __restrict__ scr, float* __restrict__ rede) {
  float* __restrict__ rm0 = scr;             // 4 x 256 floats
  float* __restrict__ rM0 = scr + 256;
  float* __restrict__ rm1 = scr + 512;
  float* __restrict__ rM1 = scr + 768;
  const int tid = threadIdx.x;
  float mnp = 3.4e38f, mxp = 0.f, mnt = 3.4e38f, mxt = 0.f;
  for (int j = tid; j < 1024; j += 256) {    // vol0 = 0..1023 (vol-major idx)
    mnp = fminf(mnp, fminS[j]);
    mxp = fmaxf(mxp, fmaxS[j]);
    mnt = fminf(mnt, fminS[1024 + j]);       // vol1 = 1024..2047
    mxt = fmaxf(mxt, fmaxS[1024 + j]);
  }
  rm0[tid] = mnp; rM0[tid] = mxp; rm1[tid] = mnt; rM1[tid] = mxt;
  __syncthreads();
  for (int s = 128; s > 0; s >>= 1) {
    if (tid < s) {
      rm0[tid] = fminf(rm0[tid], rm0[tid + s]);
      rM0[tid] = fmaxf(rM0[tid], rM0[tid + s]);
      rm1[tid] = fminf(rm1[tid], rm1[tid + s]);
      rM1[tid] = fmaxf(rM1[tid], rM1[tid + s]);
    }
    __syncthreads();
  }
  mnp = rm0[0]; mxp = rM0[0]; mnt = rm1[0]; mxt = rM1[0];
  const float scp = 1.f / (mxp - mnp + 1e-6f);
  const float sct = 1.f / (mxt - mnt + 1e-6f);
  const h8* __restrict__ gp = (const h8*)gmP;
  const h8* __restrict__ gt = (const h8*)gmT;
  float lsum = 0.f;
  const int base = bidx << 9;                      // 512 h8 per block
#pragma unroll
  for (int i = 0; i < 2; ++i) {
    const int idx = base + (i << 8) + tid;
    const h8 a = gp[idx];
    const h8 b = gt[idx];
#pragma unroll
    for (int j = 0; j < 8; ++j)
      lsum += fabsf(((float)a[j] - mnp) * scp - ((float)b[j] - mnt) * sct);
  }
  rede[tid] = lsum;
  __syncthreads();
  for (int s = 128; s > 0; s >>= 1) {
    if (tid < s) rede[tid] += rede[tid + s];
    __syncthreads();
  }
  if (tid == 0) absS[bidx] = (double)rede[0];   // plain store, once
}

// ---- L3: z-blur+ssim (4 z/thread, zero-LDS) || edge (bid%3, r25) -----------
// SSIM from s/d fields: S2=mus^2, D2=mud^2:
//   num = ((S2-D2)/2 + C1) * ((G(ss)-G(dd)-S2+D2)/2 + C2)
//   den = ((S2+D2)/2 + C1) * ((G(ss)+G(dd)-S2-D2)/2 + C2)
__global__ __launch_bounds__(256) void k_zblur_ssim(
    const _Float16* __restrict__ B, double* __restrict__ ssimS,
    const _Float16* __restrict__ gmP, const _Float16* __restrict__ gmT,
    const float* __restrict__ fminS, const float* __restrict__ fmaxS,
    double* __restrict__ absS) {
  __shared__ float scr[1024];
  __shared__ float red[256];
  const int tid = threadIdx.x;
  const int bid = blockIdx.x;                 // 0..3071
  const int wg = ((bid & 7) * 384) + (bid >> 3);   // XCD-chunk (bijective)
  const int r3 = wg % 3;
  if (r3 == 2) {
    edge_body(gmP, gmT, fminS, fmaxS, absS, wg / 3, scr, red);    // 0..1023
    return;
  }
  const int idx = (wg / 3) * 2 + r3;                     // 0..2047
  const int zseg = idx & 7;                   // zseg fastest: halo adjacency
  const int y = (idx >> 3) & 127;
  const int batch = idx >> 10;
  const int xc = tid & 63;
  const int zg = tid >> 6;                    // 0..3
  const h8* __restrict__ Bh = (const h8*)B;
  const int col8 = (batch << 20) + (y << 6);  // h8 idx of (b,0,y,0)
  const int zbase = (zseg << 4) + (zg << 2);  // first output z
  h8 m0{}, m1{}, m2{}, m3{};
#pragma unroll
  for (int k = 0; k < 14; ++k) {
    const int zz = zbase - 5 + k;
    h8 rv{};
    if ((unsigned)zz < 128u) rv = Bh[col8 + (zz << 13) + xc];
    if (k <= 10)           m0 += (_Float16)GW[k]      * rv;
    if (k >= 1 && k <= 11) m1 += (_Float16)GW[k - 1]  * rv;
    if (k >= 2 && k <= 12) m2 += (_Float16)GW[k - 2]  * rv;
    if (k >= 3)            m3 += (_Float16)GW[k - 3]  * rv;
  }
  float lsum = 0.f;
  h8 mv[4] = {m0, m1, m2, m3};
#pragma unroll
  for (int r = 0; r < 4; ++r) {
#pragma unroll
    for (int j = 0; j < 2; ++j) {             // 2 voxels per h8
      const float mus = (float)mv[r][4 * j + 0];
      const float mud = (float)mv[r][4 * j + 1];
      const float ess = (float)mv[r][4 * j + 2];
      const float edd = (float)mv[r][4 * j + 3];
      const float S2 = mus * mus, D2 = mud * mud;
      const float num = ((S2 - D2) * 0.5f + 1e-4f) *
                        ((ess - edd - S2 + D2) * 0.5f + 9e-4f);
      const float den = ((S2 + D2) * 0.5f + 1e-4f) *
                        ((ess + edd - S2 - D2) * 0.5f + 9e-4f);
      lsum += num / den;
    }
  }
  red[tid] = lsum;
  __syncthreads();
  for (int st = 128; st > 0; st >>= 1) {
    if (tid < st) red[tid] += red[tid + st];
    __syncthreads();
  }
  if (tid == 0) ssimS[idx] = (double)red[0];    // plain store, once
}

// ---- final: 256-lane parallel fold of the plain-store bins -----------------
__global__ __launch_bounds__(256) void k_final(
    const double* __restrict__ mseS, const double* __restrict__ ssimS,
    const double* __restrict__ absS, float* __restrict__ out) {
  __shared__ double dred[256];
  const int tid = threadIdx.x;
  double msl = 0.0, ssl = 0.0, abl = 0.0;
  for (int j = tid; j < 2048; j += 256) { msl += mseS[j]; ssl += ssimS[j]; }
  for (int j = tid; j < 1024; j += 256) abl += absS[j];
  dred[tid] = msl; __syncthreads();
  for (int s = 128; s > 0; s >>= 1) {
    if (tid < s) dred[tid] += dred[tid + s];
    __syncthreads();
  }
  const double ms = dred[0]; __syncthreads();
  dred[tid] = ssl; __syncthreads();
  for (int s = 128; s > 0; s >>= 1) {
    if (tid < s) dred[tid] += dred[tid + s];
    __syncthreads();
  }
  const double ss = dred[0]; __syncthreads();
  dred[tid] = abl; __syncthreads();
  for (int s = 128; s > 0; s >>= 1) {
    if (tid < s) dred[tid] += dred[tid + s];
    __syncthreads();
  }
  if (tid == 0) {
    const double ab = dred[0];
    const double N = 4194304.0;
    const double mse   = ms / N;
    const double ssiml = 1.0 - ss / N;
    const double gme   = 1e-6 + ab / N;
    const double total = mse + ssiml + 0.7 * gme;
    out[0] = (float)total;
    out[1] = (float)mse;
    out[2] = (float)ssiml;
    out[3] = (float)gme;
  }
}

extern "C" void kernel_launch(void* const* d_in, const int* in_sizes, int n_in,
                              void* d_out, int out_size, void* d_ws, size_t ws_size,
                              hipStream_t stream) {
  const float* p = (const float*)d_in[0];
  const float* t = (const float*)d_in[1];
  _Float16* A = (_Float16*)d_ws;                    // 32 MiB
  _Float16* B = A + (size_t)4 * VOL;                // 32 MiB @ 32 MiB
  char* accb = (char*)d_ws + (size_t)20 * VOL;      // @80 MiB
  double* mseS  = (double*)accb;                    // 2048 dbl
  double* ssimS = (double*)(accb + 16384);          // 2048 dbl
  double* absS  = (double*)(accb + 32768);          // 1024 dbl
  float*  fminS = (float*)(accb + 40960);           // 2048 f32
  float*  fmaxS = (float*)(accb + 49152);           // 2048 f32
  _Float16* gmP = (_Float16*)((char*)d_ws + 88080384);  // @84 MiB, 16 MiB
  _Float16* gmT = gmP + VOL;
  float* out = (float*)d_out;

  k_fused_a<<<4096, 256, 0, stream>>>(p, t, A, mseS, gmP, gmT, fminS, fmaxS);
  k_fused_b<<<2048, 256, 0, stream>>>(A, B);
  k_zblur_ssim<<<3072, 256, 0, stream>>>(B, ssimS, gmP, gmT, fminS, fmaxS,
                                         absS);
  k_final<<<1, 256, 0, stream>>>(mseS, ssimS, absS, out);
}